// Round 2
// baseline (1193.222 us; speedup 1.0000x reference)
//
#include <hip/hip_runtime.h>

typedef __attribute__((ext_vector_type(8))) __bf16 bf16x8;
typedef __attribute__((ext_vector_type(4))) float f32x4;
typedef unsigned short u16;
typedef __attribute__((ext_vector_type(4))) u16 u16x4;

#define NEGINF -3.0e38f
#define LOG2E 1.4426950408889634f

__device__ inline f32x4 zero4() { f32x4 v; v[0]=0.f; v[1]=0.f; v[2]=0.f; v[3]=0.f; return v; }

__device__ inline u16 bf16bits(float x) {
    union { __bf16 h; u16 u; } cv; cv.h = (__bf16)x; return cv.u;
}

// ---------------------------------------------------------------------------
// Convert W_Q (pre-scaled by 1/sqrt(512)), W_K, W_V to bf16 concat [1536][512].
// 384 blocks x 256 threads x 8 elements.
// ---------------------------------------------------------------------------
__global__ void convert_w(const float* __restrict__ WQ, const float* __restrict__ WK,
                          const float* __restrict__ WV, u16* __restrict__ Wb)
{
    const float qscale = 0.044194173824159216f;  // 1/sqrt(512)
    const int i8 = (blockIdx.x * 256 + threadIdx.x) * 8;
    const int seg = i8 >> 18;                    // 262144 els per W
    const int within = i8 & 262143;
    const float* src = (seg == 0) ? WQ : (seg == 1) ? WK : WV;
    const float sc = (seg == 0) ? qscale : 1.0f;
    f32x4 a = *(const f32x4*)(src + within);
    f32x4 b = *(const f32x4*)(src + within + 4);
    bf16x8 v;
    v[0]=(__bf16)(a[0]*sc); v[1]=(__bf16)(a[1]*sc); v[2]=(__bf16)(a[2]*sc); v[3]=(__bf16)(a[3]*sc);
    v[4]=(__bf16)(b[0]*sc); v[5]=(__bf16)(b[1]*sc); v[6]=(__bf16)(b[2]*sc); v[7]=(__bf16)(b[3]*sc);
    *(bf16x8*)(Wb + i8) = v;
}

// ---------------------------------------------------------------------------
// GEMM: Q/K [16384][512] bf16 and V^T tiled [b][kt64][512 d][64 kl] bf16.
// A = X f32 (convert in staging), B = Wb bf16. 128x128 tile, BK=32, 4 waves.
// grid = (12, 128): x: 0-3 Q, 4-7 K, 8-11 V.
// ---------------------------------------------------------------------------
__global__ __launch_bounds__(256, 2)
void gemm_qkv(const float* __restrict__ X, const u16* __restrict__ Wb,
              u16* __restrict__ Qb, u16* __restrict__ Kb, u16* __restrict__ Vt)
{
    __shared__ u16 As[128*32];
    __shared__ u16 Bs[128*32];
    const int t  = threadIdx.x;
    const int l  = t & 63;
    const int w  = t >> 6;
    const int c  = l & 15;
    const int qd = l >> 4;
    const int m0 = blockIdx.y * 128;
    const int nblk = blockIdx.x;
    const int n0 = nblk * 128;                  // row into Wb[1536]
    const int seg = nblk >> 2;
    const int nw0 = (nblk & 3) * 128;           // feature offset within a W
    const int wm = w >> 1, wn = w & 1;
    const int ar = t >> 2;
    const int ac = (t & 3) * 8;

    f32x4 acc[4][4];
    #pragma unroll
    for (int i = 0; i < 4; i++)
        #pragma unroll
        for (int j = 0; j < 4; j++) acc[i][j] = zero4();

    for (int kk = 0; kk < 512; kk += 32) {
        #pragma unroll
        for (int i = 0; i < 2; ++i) {
            const int r = i*64 + ar;
            const float* ga = &X[(m0 + r)*512 + kk + ac];
            f32x4 a0 = *(const f32x4*)ga;
            f32x4 a1 = *(const f32x4*)(ga + 4);
            bf16x8 va;
            va[0]=(__bf16)a0[0]; va[1]=(__bf16)a0[1]; va[2]=(__bf16)a0[2]; va[3]=(__bf16)a0[3];
            va[4]=(__bf16)a1[0]; va[5]=(__bf16)a1[1]; va[6]=(__bf16)a1[2]; va[7]=(__bf16)a1[3];
            *(bf16x8*)&As[r*32 + ac] = va;
            *(bf16x8*)&Bs[r*32 + ac] = *(const bf16x8*)&Wb[(n0 + r)*512 + kk + ac];
        }
        __syncthreads();
        bf16x8 af[4], bfr[4];
        #pragma unroll
        for (int mt = 0; mt < 4; mt++) af[mt]  = *(const bf16x8*)&As[(wm*64 + mt*16 + c)*32 + qd*8];
        #pragma unroll
        for (int nt = 0; nt < 4; nt++) bfr[nt] = *(const bf16x8*)&Bs[(wn*64 + nt*16 + c)*32 + qd*8];
        #pragma unroll
        for (int mt = 0; mt < 4; mt++)
            #pragma unroll
            for (int nt = 0; nt < 4; nt++)
                acc[mt][nt] = __builtin_amdgcn_mfma_f32_16x16x32_bf16(af[mt], bfr[nt], acc[mt][nt], 0, 0, 0);
        __syncthreads();
    }

    #pragma unroll
    for (int mt = 0; mt < 4; mt++) {
        #pragma unroll
        for (int nt = 0; nt < 4; nt++) {
            const int gm0 = m0 + wm*64 + mt*16 + qd*4;       // token row of reg 0
            const int gn  = nw0 + wn*64 + nt*16 + c;         // feature 0..511
            if (seg == 0) {
                #pragma unroll
                for (int r = 0; r < 4; r++)
                    Qb[(gm0 + r)*512 + gn] = bf16bits(acc[mt][nt][r]);
            } else if (seg == 1) {
                #pragma unroll
                for (int r = 0; r < 4; r++)
                    Kb[(gm0 + r)*512 + gn] = bf16bits(acc[mt][nt][r]);
            } else {
                const int bb = gm0 >> 12;
                const int ss = gm0 & 4095;
                const int kt = ss >> 6;
                const int kl = ss & 63;                      // 4-aligned; 4 regs contiguous
                u16x4 pk;
                pk[0] = bf16bits(acc[mt][nt][0]);
                pk[1] = bf16bits(acc[mt][nt][1]);
                pk[2] = bf16bits(acc[mt][nt][2]);
                pk[3] = bf16bits(acc[mt][nt][3]);
                *(u16x4*)&Vt[((size_t)(bb*64 + kt)*512 + gn)*64 + kl] = pk;
            }
        }
    }
}

// ---------------------------------------------------------------------------
// Flash attention, causal. M=32 query rows/block, 2 waves (128 thr), KV=32.
// 512 blocks, heavy-first (qt descending), b = x&3 for XCD/L2 locality.
// LDS 36 KB -> 4 blocks/CU; launch_bounds(128,2) -> VGPR<=256 -> 8 waves/CU.
// K tile in LDS (padded 520); V fragments straight from global (L2-hot).
// Wave w: QK rows [16w,16w+16); PV d-cols [256w,256w+256) over all 32 rows.
// ---------------------------------------------------------------------------
__global__ __launch_bounds__(128, 2)
void attn_fused(const u16* __restrict__ Qb, const u16* __restrict__ Kb,
                const u16* __restrict__ Vt, float* __restrict__ out)
{
    __shared__ u16 Ks[32*520];     // 33,280 B
    __shared__ u16 Ps[32*40];      //  2,560 B
    __shared__ float alpha_s[32];
    __shared__ float l_s[32];

    const int t  = threadIdx.x;
    const int l  = t & 63;
    const int w  = t >> 6;         // 0..1
    const int c  = l & 15;
    const int qd = l >> 4;         // 0..3
    const int x  = blockIdx.x;
    const int b  = x & 3;
    const int qt = 127 - (x >> 2); // heavy blocks dispatched first (LPT)
    const int q0 = qt * 32;

    // Q fragments, register-resident (A-layout: row=c, k=qd*8+j)
    bf16x8 qf[16];
    {
        const int qrow = b*4096 + q0 + w*16 + c;
        #pragma unroll
        for (int ks = 0; ks < 16; ++ks)
            qf[ks] = *(const bf16x8*)&Qb[(size_t)qrow*512 + ks*32 + qd*8];
    }

    f32x4 o[2][16];                // rows mt*16+qd*4+r, d = w*256 + nt*16 + c
    #pragma unroll
    for (int mt = 0; mt < 2; mt++)
        #pragma unroll
        for (int nt = 0; nt < 16; nt++) o[mt][nt] = zero4();

    float m_r[4] = {NEGINF, NEGINF, NEGINF, NEGINF};
    float l_r[4] = {0.f, 0.f, 0.f, 0.f};

    const int kr = t >> 2;         // 0..31
    const int kc = (t & 3) * 8;

    for (int it = 0; it <= qt; ++it) {
        // ---- stage K tile [32][512] -> Ks (stride 520)
        {
            const u16* Kg = &Kb[(size_t)(b*4096 + it*32 + kr)*512 + kc];
            u16* Kl = &Ks[kr*520 + kc];
            #pragma unroll
            for (int i = 0; i < 16; i++)
                *(bf16x8*)(Kl + 32*i) = *(const bf16x8*)(Kg + 32*i);
        }
        __syncthreads();

        // ---- S = Q K^T : wave's 16 rows x 32 keys
        f32x4 s[2];
        s[0] = zero4(); s[1] = zero4();
        #pragma unroll
        for (int ks = 0; ks < 16; ++ks) {
            #pragma unroll
            for (int jt = 0; jt < 2; jt++) {
                bf16x8 kf = *(const bf16x8*)&Ks[(jt*16 + c)*520 + ks*32 + qd*8];
                s[jt] = __builtin_amdgcn_mfma_f32_16x16x32_bf16(qf[ks], kf, s[jt], 0, 0, 0);
            }
        }
        if (it == qt) {            // diagonal tile: mask key > row (strip-local)
            #pragma unroll
            for (int jt = 0; jt < 2; jt++)
                #pragma unroll
                for (int r = 0; r < 4; r++)
                    if (jt*16 + c > w*16 + qd*4 + r) s[jt][r] = NEGINF;
        }

        // ---- online softmax (4 rows/lane, reduce over 16-lane groups)
        #pragma unroll
        for (int r = 0; r < 4; r++) {
            float mx = fmaxf(s[0][r], s[1][r]);
            #pragma unroll
            for (int off = 1; off < 16; off <<= 1)
                mx = fmaxf(mx, __shfl_xor(mx, off, 16));
            const float mnew = fmaxf(m_r[r], mx);
            const float al = exp2f((m_r[r] - mnew) * LOG2E);
            const float p0 = exp2f((s[0][r] - mnew) * LOG2E);
            const float p1 = exp2f((s[1][r] - mnew) * LOG2E);
            float sum = p0 + p1;
            #pragma unroll
            for (int off = 1; off < 16; off <<= 1)
                sum += __shfl_xor(sum, off, 16);
            l_r[r] = l_r[r] * al + sum;
            m_r[r] = mnew;
            const int row = w*16 + qd*4 + r;
            if (c == 0) alpha_s[row] = al;
            Ps[row*40 +  0 + c] = bf16bits(p0);
            Ps[row*40 + 16 + c] = bf16bits(p1);
        }
        __syncthreads();

        // ---- rescale O, then O += P V (V frags straight from global/L2)
        #pragma unroll
        for (int mt = 0; mt < 2; mt++) {
            f32x4 av = *(const f32x4*)&alpha_s[mt*16 + qd*4];
            #pragma unroll
            for (int nt = 0; nt < 16; nt++) {
                o[mt][nt][0] *= av[0]; o[mt][nt][1] *= av[1];
                o[mt][nt][2] *= av[2]; o[mt][nt][3] *= av[3];
            }
        }
        bf16x8 pa[2];
        #pragma unroll
        for (int mt = 0; mt < 2; mt++)
            pa[mt] = *(const bf16x8*)&Ps[(mt*16 + c)*40 + qd*8];
        const u16* Vg = &Vt[((size_t)(b*64 + (it >> 1))*512)*64 + (it & 1)*32 + qd*8];
        #pragma unroll
        for (int nt = 0; nt < 16; nt++) {
            const int d = w*256 + nt*16 + c;
            bf16x8 vb = *(const bf16x8*)(Vg + (size_t)d*64);
            #pragma unroll
            for (int mt = 0; mt < 2; mt++)
                o[mt][nt] = __builtin_amdgcn_mfma_f32_16x16x32_bf16(pa[mt], vb, o[mt][nt], 0, 0, 0);
        }
        __syncthreads();
    }

    // ---- final normalize and store
    if (c == 0) {
        #pragma unroll
        for (int r = 0; r < 4; r++) l_s[w*16 + qd*4 + r] = l_r[r];
    }
    __syncthreads();
    #pragma unroll
    for (int mt = 0; mt < 2; mt++) {
        f32x4 lv = *(const f32x4*)&l_s[mt*16 + qd*4];
        const float i0 = 1.0f / lv[0], i1 = 1.0f / lv[1];
        const float i2 = 1.0f / lv[2], i3 = 1.0f / lv[3];
        #pragma unroll
        for (int nt = 0; nt < 16; nt++) {
            float* op = &out[(size_t)(b*4096 + q0 + mt*16 + qd*4)*512 + w*256 + nt*16 + c];
            op[0]    = o[mt][nt][0] * i0;
            op[512]  = o[mt][nt][1] * i1;
            op[1024] = o[mt][nt][2] * i2;
            op[1536] = o[mt][nt][3] * i3;
        }
    }
}

extern "C" void kernel_launch(void* const* d_in, const int* in_sizes, int n_in,
                              void* d_out, int out_size, void* d_ws, size_t ws_size,
                              hipStream_t stream)
{
    (void)in_sizes; (void)n_in; (void)out_size; (void)ws_size;
    const float* X  = (const float*)d_in[0];
    const float* WQ = (const float*)d_in[1];
    const float* WK = (const float*)d_in[2];
    const float* WV = (const float*)d_in[3];
    float* out = (float*)d_out;
    char* ws = (char*)d_ws;
    u16* Qb = (u16*)(ws);                                  // 16 MB bf16 [16384][512], Q pre-scaled
    u16* Kb = (u16*)(ws + (size_t)16*1024*1024);           // 16 MB bf16 [16384][512]
    u16* Vt = (u16*)(ws + (size_t)32*1024*1024);           // 16 MB bf16 V^T tiled [4][64][512][64]
    u16* Wb = (u16*)(ws + (size_t)48*1024*1024);           // 1.5 MB bf16 [1536][512]

    convert_w<<<dim3(384), 256, 0, stream>>>(WQ, WK, WV, Wb);
    gemm_qkv<<<dim3(12, 128), 256, 0, stream>>>(X, Wb, Qb, Kb, Vt);
    attn_fused<<<dim3(512), 128, 0, stream>>>(Qb, Kb, Vt, out);
}

// Round 3
// 552.759 us; speedup vs baseline: 2.1587x; 2.1587x over previous
//
#include <hip/hip_runtime.h>

typedef __attribute__((ext_vector_type(8))) __bf16 bf16x8;
typedef __attribute__((ext_vector_type(4))) float f32x4;
typedef unsigned short u16;
typedef __attribute__((ext_vector_type(4))) u16 u16x4;

#define NEGINF -3.0e38f
#define LOG2E 1.4426950408889634f

__device__ inline f32x4 zero4() { f32x4 v; v[0]=0.f; v[1]=0.f; v[2]=0.f; v[3]=0.f; return v; }

__device__ inline u16 bf16bits(float x) {
    union { __bf16 h; u16 u; } cv; cv.h = (__bf16)x; return cv.u;
}
__device__ inline float bits2f(u16 b) {
    union { unsigned u; float f; } cv; cv.u = ((unsigned)b) << 16; return cv.f;
}

// async 16B/lane global -> LDS (lds dest = wave-uniform base + lane*16)
__device__ inline void load_lds16(const u16* g, u16* l) {
    __builtin_amdgcn_global_load_lds((const __attribute__((address_space(1))) void*)g,
                                     (__attribute__((address_space(3))) void*)l, 16, 0, 0);
}

// ---------------------------------------------------------------------------
// Convert W_Q (pre-scaled by 1/sqrt(512)), W_K, W_V to bf16 concat [1536][512].
// ---------------------------------------------------------------------------
__global__ void convert_w(const float* __restrict__ WQ, const float* __restrict__ WK,
                          const float* __restrict__ WV, u16* __restrict__ Wb)
{
    const float qscale = 0.044194173824159216f;  // 1/sqrt(512)
    const int i8 = (blockIdx.x * 256 + threadIdx.x) * 8;
    const int seg = i8 >> 18;                    // 262144 els per W
    const int within = i8 & 262143;
    const float* src = (seg == 0) ? WQ : (seg == 1) ? WK : WV;
    const float sc = (seg == 0) ? qscale : 1.0f;
    f32x4 a = *(const f32x4*)(src + within);
    f32x4 b = *(const f32x4*)(src + within + 4);
    bf16x8 v;
    v[0]=(__bf16)(a[0]*sc); v[1]=(__bf16)(a[1]*sc); v[2]=(__bf16)(a[2]*sc); v[3]=(__bf16)(a[3]*sc);
    v[4]=(__bf16)(b[0]*sc); v[5]=(__bf16)(b[1]*sc); v[6]=(__bf16)(b[2]*sc); v[7]=(__bf16)(b[3]*sc);
    *(bf16x8*)(Wb + i8) = v;
}

// ---------------------------------------------------------------------------
// GEMM: Q/K [16384][512] bf16 and V^T tiled [b][kt64][512 d][64 kl] bf16.
// A = X f32 (register convert), B = Wb bf16 via global_load_lds width-16.
// 128x128 tile, BK=32, 4 waves. grid = (12, 128): x: 0-3 Q, 4-7 K, 8-11 V.
// ---------------------------------------------------------------------------
__global__ __launch_bounds__(256, 2)
void gemm_qkv(const float* __restrict__ X, const u16* __restrict__ Wb,
              u16* __restrict__ Qb, u16* __restrict__ Kb, u16* __restrict__ Vt)
{
    __shared__ u16 As[128*32];
    __shared__ u16 Bs[128*32];
    const int t  = threadIdx.x;
    const int l  = t & 63;
    const int w  = t >> 6;
    const int c  = l & 15;
    const int qd = l >> 4;
    const int m0 = blockIdx.y * 128;
    const int nblk = blockIdx.x;
    const int n0 = nblk * 128;                  // row into Wb[1536]
    const int seg = nblk >> 2;
    const int nw0 = (nblk & 3) * 128;           // feature offset within a W
    const int wm = w >> 1, wn = w & 1;
    const int ar = t >> 2;
    const int ac = (t & 3) * 8;

    f32x4 acc[4][4];
    #pragma unroll
    for (int i = 0; i < 4; i++)
        #pragma unroll
        for (int j = 0; j < 4; j++) acc[i][j] = zero4();

    for (int kk = 0; kk < 512; kk += 32) {
        // B tile via async global->LDS: wave w stages rows [w*32, w*32+32)
        #pragma unroll
        for (int i = 0; i < 2; ++i) {
            const int r0 = w*32 + i*16;
            load_lds16(&Wb[(size_t)(n0 + r0 + (l >> 2))*512 + kk + (l & 3)*8], &Bs[r0*32]);
        }
        // A tile: f32 load + convert in registers
        #pragma unroll
        for (int i = 0; i < 2; ++i) {
            const int r = i*64 + ar;
            const float* ga = &X[(size_t)(m0 + r)*512 + kk + ac];
            f32x4 a0 = *(const f32x4*)ga;
            f32x4 a1 = *(const f32x4*)(ga + 4);
            bf16x8 va;
            va[0]=(__bf16)a0[0]; va[1]=(__bf16)a0[1]; va[2]=(__bf16)a0[2]; va[3]=(__bf16)a0[3];
            va[4]=(__bf16)a1[0]; va[5]=(__bf16)a1[1]; va[6]=(__bf16)a1[2]; va[7]=(__bf16)a1[3];
            *(bf16x8*)&As[r*32 + ac] = va;
        }
        __syncthreads();
        bf16x8 af[4], bfr[4];
        #pragma unroll
        for (int mt = 0; mt < 4; mt++) af[mt]  = *(const bf16x8*)&As[(wm*64 + mt*16 + c)*32 + qd*8];
        #pragma unroll
        for (int nt = 0; nt < 4; nt++) bfr[nt] = *(const bf16x8*)&Bs[(wn*64 + nt*16 + c)*32 + qd*8];
        #pragma unroll
        for (int mt = 0; mt < 4; mt++)
            #pragma unroll
            for (int nt = 0; nt < 4; nt++)
                acc[mt][nt] = __builtin_amdgcn_mfma_f32_16x16x32_bf16(af[mt], bfr[nt], acc[mt][nt], 0, 0, 0);
        __syncthreads();
    }

    #pragma unroll
    for (int mt = 0; mt < 4; mt++) {
        #pragma unroll
        for (int nt = 0; nt < 4; nt++) {
            const int gm0 = m0 + wm*64 + mt*16 + qd*4;       // token row of reg 0
            const int gn  = nw0 + wn*64 + nt*16 + c;         // feature 0..511
            if (seg == 0) {
                #pragma unroll
                for (int r = 0; r < 4; r++)
                    Qb[(size_t)(gm0 + r)*512 + gn] = bf16bits(acc[mt][nt][r]);
            } else if (seg == 1) {
                #pragma unroll
                for (int r = 0; r < 4; r++)
                    Kb[(size_t)(gm0 + r)*512 + gn] = bf16bits(acc[mt][nt][r]);
            } else {
                const int bb = gm0 >> 12;
                const int ss = gm0 & 4095;
                const int kt = ss >> 6;
                const int kl = ss & 63;                      // 4-aligned; 4 regs contiguous
                u16x4 pk;
                pk[0] = bf16bits(acc[mt][nt][0]);
                pk[1] = bf16bits(acc[mt][nt][1]);
                pk[2] = bf16bits(acc[mt][nt][2]);
                pk[3] = bf16bits(acc[mt][nt][3]);
                *(u16x4*)&Vt[((size_t)(bb*64 + kt)*512 + gn)*64 + kl] = pk;
            }
        }
    }
}

// ---------------------------------------------------------------------------
// Flash attention chunk (flash-decoding k-split), causal.
// Block = (b, qt, j): M=64 query rows (q-tile qt), KV-iters [16j, min(qt,16j+15)],
// KV tile 64. 4 waves, 256 thr. Writes UNNORMALIZED partial O (bf16) + m,l.
// grid (256,4): x = qt*4+j (empty chunks return), y = b.
// LDS: K tile 66.5KB (stride 520) + Ps 9.2KB -> 2 blocks/CU, 8 waves/CU.
// K staged via global_load_lds, issued after mid-barrier (overlaps PV).
// V fragments read from global V^T tiles (L2/L3-hot).
// ---------------------------------------------------------------------------
__global__ __launch_bounds__(256, 2)
void attn_chunk(const u16* __restrict__ Qb, const u16* __restrict__ Kb,
                const u16* __restrict__ Vt, u16* __restrict__ Op,
                float* __restrict__ Mp, float* __restrict__ Lp)
{
    __shared__ u16 Ks[64*520];     // 66,560 B
    __shared__ u16 Ps[64*72];      //  9,216 B
    __shared__ float alpha_s[64];

    const int t  = threadIdx.x;
    const int l  = t & 63;
    const int w  = t >> 6;         // 0..3
    const int c  = l & 15;
    const int qd = l >> 4;         // 0..3
    const int b  = blockIdx.y;
    const int qt = blockIdx.x >> 2;
    const int j  = blockIdx.x & 3;
    if (j*16 > qt) return;         // empty chunk slot
    const int it0 = j*16;
    const int it1 = min(qt, it0 + 15);
    const int q0 = qt * 64;

    // Q fragments, register-resident (A-layout: row=c, k=qd*8+jj)
    bf16x8 qf[16];
    {
        const size_t qrow = (size_t)(b*4096 + q0 + w*16 + c);
        #pragma unroll
        for (int ks = 0; ks < 16; ++ks)
            qf[ks] = *(const bf16x8*)&Qb[qrow*512 + ks*32 + qd*8];
    }

    f32x4 o[4][8];                 // rows mt*16+qd*4+r, d = w*128 + nt*16 + c
    #pragma unroll
    for (int mt = 0; mt < 4; mt++)
        #pragma unroll
        for (int nt = 0; nt < 8; nt++) o[mt][nt] = zero4();

    float m_r[4] = {NEGINF, NEGINF, NEGINF, NEGINF};
    float l_r[4] = {0.f, 0.f, 0.f, 0.f};

    const u16* Kg = &Kb[(size_t)(b*4096)*512];

    // prefetch first K tile (wave w stages rows [16w,16w+16))
    #pragma unroll
    for (int i = 0; i < 16; i++) {
        const int row = w*16 + i;
        load_lds16(Kg + ((size_t)(it0*64 + row))*512 + l*8, &Ks[row*520]);
    }

    for (int it = it0; it <= it1; ++it) {
        __syncthreads();           // drains staging vmcnt + barrier

        // ---- S = Q K^T : wave's 16 rows x 64 keys
        f32x4 s[4];
        #pragma unroll
        for (int jt = 0; jt < 4; jt++) s[jt] = zero4();
        #pragma unroll
        for (int ks = 0; ks < 16; ++ks) {
            #pragma unroll
            for (int jt = 0; jt < 4; jt++) {
                bf16x8 kf = *(const bf16x8*)&Ks[(jt*16 + c)*520 + ks*32 + qd*8];
                s[jt] = __builtin_amdgcn_mfma_f32_16x16x32_bf16(qf[ks], kf, s[jt], 0, 0, 0);
            }
        }
        if (it == qt) {            // diagonal tile: mask key > row
            #pragma unroll
            for (int jt = 0; jt < 4; jt++)
                #pragma unroll
                for (int r = 0; r < 4; r++)
                    if (jt*16 + c > w*16 + qd*4 + r) s[jt][r] = NEGINF;
        }

        // ---- online softmax (4 rows/lane, reduce over 16-lane groups)
        #pragma unroll
        for (int r = 0; r < 4; r++) {
            float mx = fmaxf(fmaxf(s[0][r], s[1][r]), fmaxf(s[2][r], s[3][r]));
            #pragma unroll
            for (int off = 1; off < 16; off <<= 1)
                mx = fmaxf(mx, __shfl_xor(mx, off, 16));
            const float mnew = fmaxf(m_r[r], mx);
            const float al = exp2f((m_r[r] - mnew) * LOG2E);
            const float p0 = exp2f((s[0][r] - mnew) * LOG2E);
            const float p1 = exp2f((s[1][r] - mnew) * LOG2E);
            const float p2 = exp2f((s[2][r] - mnew) * LOG2E);
            const float p3 = exp2f((s[3][r] - mnew) * LOG2E);
            float sum = (p0 + p1) + (p2 + p3);
            #pragma unroll
            for (int off = 1; off < 16; off <<= 1)
                sum += __shfl_xor(sum, off, 16);
            l_r[r] = l_r[r] * al + sum;
            m_r[r] = mnew;
            const int row = w*16 + qd*4 + r;
            if (c == 0) alpha_s[row] = al;
            Ps[row*72 +  0 + c] = bf16bits(p0);
            Ps[row*72 + 16 + c] = bf16bits(p1);
            Ps[row*72 + 32 + c] = bf16bits(p2);
            Ps[row*72 + 48 + c] = bf16bits(p3);
        }
        __syncthreads();           // Ps/alpha ready; all QK reads of Ks done

        // ---- issue next K tile staging NOW (overlaps with PV below)
        if (it < it1) {
            #pragma unroll
            for (int i = 0; i < 16; i++) {
                const int row = w*16 + i;
                load_lds16(Kg + ((size_t)((it+1)*64 + row))*512 + l*8, &Ks[row*520]);
            }
        }

        // ---- rescale O, then O += P V (V frags from global/L2)
        #pragma unroll
        for (int mt = 0; mt < 4; mt++) {
            f32x4 av = *(const f32x4*)&alpha_s[mt*16 + qd*4];
            #pragma unroll
            for (int nt = 0; nt < 8; nt++) {
                o[mt][nt][0] *= av[0]; o[mt][nt][1] *= av[1];
                o[mt][nt][2] *= av[2]; o[mt][nt][3] *= av[3];
            }
        }
        const u16* Vg = &Vt[((size_t)(b*64 + it)*512)*64];
        #pragma unroll
        for (int ks2 = 0; ks2 < 2; ++ks2) {
            bf16x8 pa[4];
            #pragma unroll
            for (int mt = 0; mt < 4; mt++)
                pa[mt] = *(const bf16x8*)&Ps[(mt*16 + c)*72 + ks2*32 + qd*8];
            #pragma unroll
            for (int nt = 0; nt < 8; nt++) {
                const int d = w*128 + nt*16 + c;
                bf16x8 vb = *(const bf16x8*)(Vg + (size_t)d*64 + ks2*32 + qd*8);
                #pragma unroll
                for (int mt = 0; mt < 4; mt++)
                    o[mt][nt] = __builtin_amdgcn_mfma_f32_16x16x32_bf16(pa[mt], vb, o[mt][nt], 0, 0, 0);
            }
        }
    }

    // ---- write unnormalized partials + m, l
    const size_t ob = ((size_t)((b*64 + qt)*4 + j))*64;
    if (c == 0) {
        const size_t rb = ob + w*16 + qd*4;
        #pragma unroll
        for (int r = 0; r < 4; r++) { Mp[rb + r] = m_r[r]; Lp[rb + r] = l_r[r]; }
    }
    #pragma unroll
    for (int mt = 0; mt < 4; mt++)
        #pragma unroll
        for (int nt = 0; nt < 8; nt++)
            #pragma unroll
            for (int r = 0; r < 4; r++)
                Op[(ob + mt*16 + qd*4 + r)*512 + w*128 + nt*16 + c] = bf16bits(o[mt][nt][r]);
}

// ---------------------------------------------------------------------------
// Combine partial chunks: out = sum_j e^{m_j-M} O_j / sum_j e^{m_j-M} l_j.
// grid (64, 4) = (qt, b), 256 threads.
// ---------------------------------------------------------------------------
__global__ __launch_bounds__(256)
void combine(const u16* __restrict__ Op, const float* __restrict__ Mp,
             const float* __restrict__ Lp, float* __restrict__ out)
{
    __shared__ float sc[4][64];
    const int t  = threadIdx.x;
    const int qt = blockIdx.x;
    const int b  = blockIdx.y;
    const int nc = (qt >> 4) + 1;
    const int base = (b*64 + qt)*4;

    if (t < 64) {
        float mj[4], lj[4];
        float M = NEGINF;
        for (int j = 0; j < nc; j++) {
            mj[j] = Mp[(base + j)*64 + t];
            lj[j] = Lp[(base + j)*64 + t];
            M = fmaxf(M, mj[j]);
        }
        float wj[4];
        float denom = 0.f;
        for (int j = 0; j < nc; j++) {
            wj[j] = exp2f((mj[j] - M) * LOG2E);
            denom += wj[j] * lj[j];
        }
        const float inv = 1.0f / denom;
        for (int j = 0; j < nc; j++) sc[j][t] = wj[j] * inv;
    }
    __syncthreads();

    const int c4 = (t & 127) * 4;
    const int r0 = (t >> 7) * 32;
    for (int r = r0; r < r0 + 32; ++r) {
        float a0 = 0.f, a1 = 0.f, a2 = 0.f, a3 = 0.f;
        for (int j = 0; j < nc; j++) {
            const float s = sc[j][r];
            u16x4 v = *(const u16x4*)&Op[((size_t)(base + j)*64 + r)*512 + c4];
            a0 += s * bits2f(v[0]); a1 += s * bits2f(v[1]);
            a2 += s * bits2f(v[2]); a3 += s * bits2f(v[3]);
        }
        f32x4 res; res[0]=a0; res[1]=a1; res[2]=a2; res[3]=a3;
        *(f32x4*)&out[((size_t)(b*4096 + qt*64 + r))*512 + c4] = res;
    }
}

extern "C" void kernel_launch(void* const* d_in, const int* in_sizes, int n_in,
                              void* d_out, int out_size, void* d_ws, size_t ws_size,
                              hipStream_t stream)
{
    (void)in_sizes; (void)n_in; (void)out_size; (void)ws_size;
    const float* X  = (const float*)d_in[0];
    const float* WQ = (const float*)d_in[1];
    const float* WK = (const float*)d_in[2];
    const float* WV = (const float*)d_in[3];
    float* out = (float*)d_out;
    char* ws = (char*)d_ws;
    const size_t MB = 1024*1024;
    u16*   Qb = (u16*)(ws);              // 16 MB bf16 [16384][512], Q pre-scaled
    u16*   Kb = (u16*)(ws + 16*MB);      // 16 MB bf16 [16384][512]
    u16*   Vt = (u16*)(ws + 32*MB);      // 16 MB bf16 V^T tiled [4][64][512][64]
    u16*   Wb = (u16*)(ws + 48*MB);      //  1.5 MB bf16 [1536][512]
    float* Mp = (float*)(ws + 50*MB);    //  256 KB [4][64][4][64]
    float* Lp = (float*)(ws + 51*MB);    //  256 KB
    u16*   Op = (u16*)(ws + 52*MB);      // 64 MB bf16 [4][64][4][64][512]  (ws total ~116 MB)

    convert_w<<<dim3(384), 256, 0, stream>>>(WQ, WK, WV, Wb);
    gemm_qkv<<<dim3(12, 128), 256, 0, stream>>>(X, Wb, Qb, Kb, Vt);
    attn_chunk<<<dim3(256, 4), 256, 0, stream>>>(Qb, Kb, Vt, Op, Mp, Lp);
    combine<<<dim3(64, 4), 256, 0, stream>>>(Op, Mp, Lp, out);
}

// Round 5
// 490.922 us; speedup vs baseline: 2.4306x; 1.1260x over previous
//
#include <hip/hip_runtime.h>

typedef __attribute__((ext_vector_type(8))) __bf16 bf16x8;
typedef __attribute__((ext_vector_type(4))) float f32x4;
typedef unsigned short u16;
typedef __attribute__((ext_vector_type(4))) u16 u16x4;

#define NEGINF -3.0e38f
#define LOG2E 1.4426950408889634f

__device__ inline f32x4 zero4() { f32x4 v; v[0]=0.f; v[1]=0.f; v[2]=0.f; v[3]=0.f; return v; }

__device__ inline u16 bf16bits(float x) {
    union { __bf16 h; u16 u; } cv; cv.h = (__bf16)x; return cv.u;
}
__device__ inline float bits2f(u16 b) {
    union { unsigned u; float f; } cv; cv.u = ((unsigned)b) << 16; return cv.f;
}

// async 16B/lane global -> LDS (lds dest = wave-uniform base + lane*16)
__device__ inline void load_lds16(const u16* g, u16* l) {
    __builtin_amdgcn_global_load_lds((const __attribute__((address_space(1))) void*)g,
                                     (__attribute__((address_space(3))) void*)l, 16, 0, 0);
}

// ---------------------------------------------------------------------------
// Convert W_Q (pre-scaled by 1/sqrt(512)), W_K, W_V to bf16 concat [1536][512].
// ---------------------------------------------------------------------------
__global__ void convert_w(const float* __restrict__ WQ, const float* __restrict__ WK,
                          const float* __restrict__ WV, u16* __restrict__ Wb)
{
    const float qscale = 0.044194173824159216f;  // 1/sqrt(512)
    const int i8 = (blockIdx.x * 256 + threadIdx.x) * 8;
    const int seg = i8 >> 18;                    // 262144 els per W
    const int within = i8 & 262143;
    const float* src = (seg == 0) ? WQ : (seg == 1) ? WK : WV;
    const float sc = (seg == 0) ? qscale : 1.0f;
    f32x4 a = *(const f32x4*)(src + within);
    f32x4 b = *(const f32x4*)(src + within + 4);
    bf16x8 v;
    v[0]=(__bf16)(a[0]*sc); v[1]=(__bf16)(a[1]*sc); v[2]=(__bf16)(a[2]*sc); v[3]=(__bf16)(a[3]*sc);
    v[4]=(__bf16)(b[0]*sc); v[5]=(__bf16)(b[1]*sc); v[6]=(__bf16)(b[2]*sc); v[7]=(__bf16)(b[3]*sc);
    *(bf16x8*)(Wb + i8) = v;
}

// ---------------------------------------------------------------------------
// Convert X f32 -> bf16. 16384*512 = 8,388,608 els = 4096 blocks x 256 x 8.
// ---------------------------------------------------------------------------
__global__ void convert_x(const float* __restrict__ X, u16* __restrict__ Xb)
{
    const size_t i8 = ((size_t)blockIdx.x * 256 + threadIdx.x) * 8;
    f32x4 a = *(const f32x4*)(X + i8);
    f32x4 b = *(const f32x4*)(X + i8 + 4);
    bf16x8 v;
    v[0]=(__bf16)a[0]; v[1]=(__bf16)a[1]; v[2]=(__bf16)a[2]; v[3]=(__bf16)a[3];
    v[4]=(__bf16)b[0]; v[5]=(__bf16)b[1]; v[6]=(__bf16)b[2]; v[7]=(__bf16)b[3];
    *(bf16x8*)(Xb + i8) = v;
}

// ---------------------------------------------------------------------------
// GEMM: Q/K [16384][512] bf16 and V^T tiled [b][kt32 (128)][512 d][32 kl] bf16.
// A = Xb bf16, B = Wb bf16, both staged via global_load_lds width-16.
// 128x128 tile, BK=32, 4 waves. grid = (12, 128): x: 0-3 Q, 4-7 K, 8-11 V.
// ---------------------------------------------------------------------------
__global__ __launch_bounds__(256, 2)
void gemm_qkv(const u16* __restrict__ Xb, const u16* __restrict__ Wb,
              u16* __restrict__ Qb, u16* __restrict__ Kb, u16* __restrict__ Vt)
{
    __shared__ u16 As[128*32];
    __shared__ u16 Bs[128*32];
    const int t  = threadIdx.x;
    const int l  = t & 63;
    const int w  = t >> 6;
    const int c  = l & 15;
    const int qd = l >> 4;
    const int m0 = blockIdx.y * 128;
    const int nblk = blockIdx.x;
    const int n0 = nblk * 128;                  // row into Wb[1536]
    const int seg = nblk >> 2;
    const int nw0 = (nblk & 3) * 128;           // feature offset within a W
    const int wm = w >> 1, wn = w & 1;
    const int lr = l >> 2;                      // 0..15 row-within-instr
    const int lc = (l & 3) * 8;                 // 8-el chunk

    f32x4 acc[4][4];
    #pragma unroll
    for (int i = 0; i < 4; i++)
        #pragma unroll
        for (int j = 0; j < 4; j++) acc[i][j] = zero4();

    for (int kk = 0; kk < 512; kk += 32) {
        // wave w stages A rows [32w,32w+32) and B rows [32w,32w+32)
        #pragma unroll
        for (int i = 0; i < 2; ++i) {
            const int r0 = w*32 + i*16;
            load_lds16(&Xb[(size_t)(m0 + r0 + lr)*512 + kk + lc], &As[r0*32]);
            load_lds16(&Wb[(size_t)(n0 + r0 + lr)*512 + kk + lc], &Bs[r0*32]);
        }
        __syncthreads();
        bf16x8 af[4], bfr[4];
        #pragma unroll
        for (int mt = 0; mt < 4; mt++) af[mt]  = *(const bf16x8*)&As[(wm*64 + mt*16 + c)*32 + qd*8];
        #pragma unroll
        for (int nt = 0; nt < 4; nt++) bfr[nt] = *(const bf16x8*)&Bs[(wn*64 + nt*16 + c)*32 + qd*8];
        #pragma unroll
        for (int mt = 0; mt < 4; mt++)
            #pragma unroll
            for (int nt = 0; nt < 4; nt++)
                acc[mt][nt] = __builtin_amdgcn_mfma_f32_16x16x32_bf16(af[mt], bfr[nt], acc[mt][nt], 0, 0, 0);
        __syncthreads();
    }

    #pragma unroll
    for (int mt = 0; mt < 4; mt++) {
        #pragma unroll
        for (int nt = 0; nt < 4; nt++) {
            const int gm0 = m0 + wm*64 + mt*16 + qd*4;       // token row of reg 0
            const int gn  = nw0 + wn*64 + nt*16 + c;         // feature 0..511
            if (seg == 0) {
                #pragma unroll
                for (int r = 0; r < 4; r++)
                    Qb[(size_t)(gm0 + r)*512 + gn] = bf16bits(acc[mt][nt][r]);
            } else if (seg == 1) {
                #pragma unroll
                for (int r = 0; r < 4; r++)
                    Kb[(size_t)(gm0 + r)*512 + gn] = bf16bits(acc[mt][nt][r]);
            } else {
                const int bb = gm0 >> 12;
                const int ss = gm0 & 4095;
                const int kt = ss >> 5;                      // 32-key tile
                const int kl = ss & 31;                      // 4-aligned
                u16x4 pk;
                pk[0] = bf16bits(acc[mt][nt][0]);
                pk[1] = bf16bits(acc[mt][nt][1]);
                pk[2] = bf16bits(acc[mt][nt][2]);
                pk[3] = bf16bits(acc[mt][nt][3]);
                *(u16x4*)&Vt[((size_t)(bb*128 + kt)*512 + gn)*32 + kl] = pk;
            }
        }
    }
}

// ---------------------------------------------------------------------------
// Flash attention chunk, wave-independent. Block = 4 waves x 16 Q-rows each,
// full D=512 per wave. KV tile = 32 keys, double-buffered Ks via
// global_load_lds. ONE __syncthreads per KV tile (staging sync only).
// P transposes through per-wave LDS region (no barrier). alpha in registers.
// Chunking: 4 chunks per qt, u = ceil(2(qt+1)/4) KV-32 units per chunk.
// grid 1024: qt = 63-(x>>4) (heavy first), j = (x>>2)&3, b = x&3.
// Writes unnormalized partial O (bf16) + m, l per row.
// ---------------------------------------------------------------------------
__global__ __launch_bounds__(256, 2)
void attn_chunk(const u16* __restrict__ Qb, const u16* __restrict__ Kb,
                const u16* __restrict__ Vt, u16* __restrict__ Op,
                float* __restrict__ Mp, float* __restrict__ Lp)
{
    __shared__ u16 Ks[2][32*520];  // 66,560 B (rows padded to 520; each row is
                                   // 1024B contiguous -> load_lds16-legal)
    __shared__ u16 Ps[4][16*40];   //  5,120 B, per-wave P transpose buffer

    const int t  = threadIdx.x;
    const int l  = t & 63;
    const int w  = t >> 6;         // 0..3: Q-row strip [16w,16w+16)
    const int c  = l & 15;
    const int qd = l >> 4;         // 0..3
    const int x  = blockIdx.x;
    const int qt = 63 - (x >> 4);
    const int j  = (x >> 2) & 3;
    const int b  = x & 3;
    const int unitsTotal = (qt + 1) * 2;       // KV-32 units in [0, 2qt+2)
    const int u  = (unitsTotal + 3) >> 2;      // units per chunk
    const int it0 = j * u;
    if (it0 >= unitsTotal) return;             // empty chunk (whole block)
    const int it1 = min(unitsTotal, it0 + u) - 1;
    const int q0 = qt * 64;

    // Q fragments, register-resident (A-layout: row=c, k=qd*8+jj)
    bf16x8 qf[16];
    {
        const size_t qrow = (size_t)(b*4096 + q0 + w*16 + c);
        #pragma unroll
        for (int ks = 0; ks < 16; ++ks)
            qf[ks] = *(const bf16x8*)&Qb[qrow*512 + ks*32 + qd*8];
    }

    f32x4 o[32];                   // row=qd*4+r (strip-local), d = nt*16 + c
    #pragma unroll
    for (int nt = 0; nt < 32; nt++) o[nt] = zero4();

    float m_r[4] = {NEGINF, NEGINF, NEGINF, NEGINF};
    float l_r[4] = {0.f, 0.f, 0.f, 0.f};

    const u16* Kg = &Kb[(size_t)(b*4096)*512];
    u16* Pw = &Ps[w][0];

    // stage first K tile into buf 0: wave w stages key-rows [8w, 8w+8)
    #pragma unroll
    for (int i = 0; i < 8; i++) {
        const int row = w*8 + i;
        load_lds16(Kg + ((size_t)(it0*32 + row))*512 + l*8, &Ks[0][row*520]);
    }

    for (int it = it0; it <= it1; ++it) {
        const int buf = (it - it0) & 1;
        __syncthreads();           // staging of `it` done; prev buffer free

        // ---- S = Q K^T : wave's 16 rows x 32 keys
        f32x4 s[2];
        s[0] = zero4(); s[1] = zero4();
        #pragma unroll
        for (int ks = 0; ks < 16; ++ks) {
            #pragma unroll
            for (int jt = 0; jt < 2; jt++) {
                bf16x8 kf = *(const bf16x8*)&Ks[buf][(jt*16 + c)*520 + ks*32 + qd*8];
                s[jt] = __builtin_amdgcn_mfma_f32_16x16x32_bf16(qf[ks], kf, s[jt], 0, 0, 0);
            }
        }
        if (it >= 2*qt) {          // diagonal units: mask key > row
            const int koff = (it - 2*qt) * 32;   // 0 or 32, relative to q0
            #pragma unroll
            for (int jt = 0; jt < 2; jt++)
                #pragma unroll
                for (int r = 0; r < 4; r++)
                    if (koff + jt*16 + c > w*16 + qd*4 + r) s[jt][r] = NEGINF;
        }

        // ---- online softmax (4 rows/lane, reduce over 16-lane groups)
        float alr[4];
        #pragma unroll
        for (int r = 0; r < 4; r++) {
            float mx = fmaxf(s[0][r], s[1][r]);
            #pragma unroll
            for (int off = 1; off < 16; off <<= 1)
                mx = fmaxf(mx, __shfl_xor(mx, off, 16));
            const float mnew = fmaxf(m_r[r], mx);
            const float al = exp2f((m_r[r] - mnew) * LOG2E);
            const float p0 = exp2f((s[0][r] - mnew) * LOG2E);
            const float p1 = exp2f((s[1][r] - mnew) * LOG2E);
            float sum = p0 + p1;
            #pragma unroll
            for (int off = 1; off < 16; off <<= 1)
                sum += __shfl_xor(sum, off, 16);
            l_r[r] = l_r[r] * al + sum;
            m_r[r] = mnew;
            alr[r] = al;
            Pw[(qd*4 + r)*40 +  0 + c] = bf16bits(p0);
            Pw[(qd*4 + r)*40 + 16 + c] = bf16bits(p1);
        }

        // ---- issue next K tile staging (drains at next barrier, behind PV)
        if (it < it1) {
            #pragma unroll
            for (int i = 0; i < 8; i++) {
                const int row = w*8 + i;
                load_lds16(Kg + ((size_t)((it+1)*32 + row))*512 + l*8,
                           &Ks[buf ^ 1][row*520]);
            }
        }

        // ---- P fragment (per-wave LDS, in-order DS pipe, no barrier needed)
        bf16x8 pav = *(const bf16x8*)&Pw[c*40 + qd*8];

        // ---- rescale O and accumulate P*V (V from global, 1KB/instr coalesced)
        const u16* Vg = &Vt[((size_t)(b*128 + it)*512)*32 + qd*8];
        #pragma unroll
        for (int nt = 0; nt < 32; nt++) {
            bf16x8 vb = *(const bf16x8*)(Vg + (nt*16 + c)*32);
            o[nt][0] *= alr[0]; o[nt][1] *= alr[1];
            o[nt][2] *= alr[2]; o[nt][3] *= alr[3];
            o[nt] = __builtin_amdgcn_mfma_f32_16x16x32_bf16(pav, vb, o[nt], 0, 0, 0);
        }
    }

    // ---- write unnormalized partials + m, l
    const size_t ob = ((size_t)((b*64 + qt)*4 + j))*64;
    if (c == 0) {
        const size_t rb = ob + w*16 + qd*4;
        #pragma unroll
        for (int r = 0; r < 4; r++) { Mp[rb + r] = m_r[r]; Lp[rb + r] = l_r[r]; }
    }
    #pragma unroll
    for (int nt = 0; nt < 32; nt++)
        #pragma unroll
        for (int r = 0; r < 4; r++)
            Op[(ob + w*16 + qd*4 + r)*512 + nt*16 + c] = bf16bits(o[nt][r]);
}

// ---------------------------------------------------------------------------
// Combine partial chunks: out = sum_j e^{m_j-M} O_j / sum_j e^{m_j-M} l_j.
// grid (64, 4) = (qt, b), 256 threads.
// ---------------------------------------------------------------------------
__global__ __launch_bounds__(256)
void combine(const u16* __restrict__ Op, const float* __restrict__ Mp,
             const float* __restrict__ Lp, float* __restrict__ out)
{
    __shared__ float sc[4][64];
    const int t  = threadIdx.x;
    const int qt = blockIdx.x;
    const int b  = blockIdx.y;
    const int unitsTotal = (qt + 1) * 2;
    const int u  = (unitsTotal + 3) >> 2;
    const int nc = (unitsTotal + u - 1) / u;   // non-empty chunks, <= 4
    const int base = (b*64 + qt)*4;

    if (t < 64) {
        float mj[4], lj[4];
        float M = NEGINF;
        for (int j = 0; j < nc; j++) {
            mj[j] = Mp[(size_t)(base + j)*64 + t];
            lj[j] = Lp[(size_t)(base + j)*64 + t];
            M = fmaxf(M, mj[j]);
        }
        float denom = 0.f;
        float wj[4];
        for (int j = 0; j < nc; j++) {
            wj[j] = exp2f((mj[j] - M) * LOG2E);
            denom += wj[j] * lj[j];
        }
        const float inv = 1.0f / denom;
        for (int j = 0; j < nc; j++) sc[j][t] = wj[j] * inv;
    }
    __syncthreads();

    const int c4 = (t & 127) * 4;
    const int r0 = (t >> 7) * 32;
    for (int r = r0; r < r0 + 32; ++r) {
        float a0 = 0.f, a1 = 0.f, a2 = 0.f, a3 = 0.f;
        for (int j = 0; j < nc; j++) {
            const float s = sc[j][r];
            u16x4 v = *(const u16x4*)&Op[((size_t)(base + j)*64 + r)*512 + c4];
            a0 += s * bits2f(v[0]); a1 += s * bits2f(v[1]);
            a2 += s * bits2f(v[2]); a3 += s * bits2f(v[3]);
        }
        f32x4 res; res[0]=a0; res[1]=a1; res[2]=a2; res[3]=a3;
        *(f32x4*)&out[((size_t)(b*4096 + qt*64 + r))*512 + c4] = res;
    }
}

extern "C" void kernel_launch(void* const* d_in, const int* in_sizes, int n_in,
                              void* d_out, int out_size, void* d_ws, size_t ws_size,
                              hipStream_t stream)
{
    (void)in_sizes; (void)n_in; (void)out_size; (void)ws_size;
    const float* X  = (const float*)d_in[0];
    const float* WQ = (const float*)d_in[1];
    const float* WK = (const float*)d_in[2];
    const float* WV = (const float*)d_in[3];
    float* out = (float*)d_out;
    char* ws = (char*)d_ws;
    const size_t MB = 1024*1024;
    u16*   Qb = (u16*)(ws);                    // [0,16) MB  bf16 [16384][512], Q pre-scaled
    u16*   Kb = (u16*)(ws + 16*MB);            // [16,32) MB bf16 [16384][512]
    u16*   Vt = (u16*)(ws + 32*MB);            // [32,48) MB bf16 V^T [4][128][512][32]
    u16*   Wb = (u16*)(ws + 48*MB);            // 1.5 MB bf16 [1536][512]
    float* Mp = (float*)(ws + 50*MB);          // 256 KB [4][64][4][64]
    float* Lp = (float*)(ws + 51*MB);          // 256 KB
    u16*   Op = (u16*)(ws + 52*MB);            // 64 MB bf16 [4][64][4][64][512] -> ws 116 MB
    u16*   Xb = (u16*)(ws + 52*MB);            // 16 MB, ALIASES Op (gemm phase only)

    convert_w<<<dim3(384), 256, 0, stream>>>(WQ, WK, WV, Wb);
    convert_x<<<dim3(4096), 256, 0, stream>>>(X, Xb);
    gemm_qkv<<<dim3(12, 128), 256, 0, stream>>>(Xb, Wb, Qb, Kb, Vt);
    attn_chunk<<<dim3(1024), 256, 0, stream>>>(Qb, Kb, Vt, Op, Mp, Lp);
    combine<<<dim3(64, 4), 256, 0, stream>>>(Op, Mp, Lp, out);
}

// Round 6
// 345.324 us; speedup vs baseline: 3.4554x; 1.4216x over previous
//
#include <hip/hip_runtime.h>

typedef __attribute__((ext_vector_type(8))) __bf16 bf16x8;
typedef __attribute__((ext_vector_type(4))) __bf16 bf16x4;
typedef __attribute__((ext_vector_type(4))) short s16x4;
typedef __attribute__((ext_vector_type(4))) float f32x4;
typedef unsigned short u16;
typedef __attribute__((ext_vector_type(4))) u16 u16x4;

#define NEGINF -3.0e38f
#define LOG2E 1.4426950408889634f

__device__ inline f32x4 zero4() { f32x4 v; v[0]=0.f; v[1]=0.f; v[2]=0.f; v[3]=0.f; return v; }

__device__ inline u16 bf16bits(float x) {
    union { __bf16 h; u16 u; } cv; cv.h = (__bf16)x; return cv.u;
}
__device__ inline float bits2f(u16 b) {
    union { unsigned u; float f; } cv; cv.u = ((unsigned)b) << 16; return cv.f;
}

__device__ inline f32x4 mfma16(bf16x4 a, bf16x4 b, f32x4 c) {
#if __has_builtin(__builtin_amdgcn_mfma_f32_16x16x16_bf16)
    return __builtin_amdgcn_mfma_f32_16x16x16_bf16(a, b, c, 0, 0, 0);
#else
    union { bf16x4 h; s16x4 s; } ua, ub; ua.h = a; ub.h = b;
    return __builtin_amdgcn_mfma_f32_16x16x16bf16_1k(ua.s, ub.s, c, 0, 0, 0);
#endif
}

// async 16B/lane global -> LDS (lds dest = wave-uniform base + lane*16)
__device__ inline void load_lds16(const u16* g, u16* l) {
    __builtin_amdgcn_global_load_lds((const __attribute__((address_space(1))) void*)g,
                                     (__attribute__((address_space(3))) void*)l, 16, 0, 0);
}

// ---------------------------------------------------------------------------
// Convert W_Q (pre-scaled by 1/sqrt(512)), W_K, W_V to bf16 concat [1536][512].
// ---------------------------------------------------------------------------
__global__ void convert_w(const float* __restrict__ WQ, const float* __restrict__ WK,
                          const float* __restrict__ WV, u16* __restrict__ Wb)
{
    const float qscale = 0.044194173824159216f;  // 1/sqrt(512)
    const int i8 = (blockIdx.x * 256 + threadIdx.x) * 8;
    const int seg = i8 >> 18;                    // 262144 els per W
    const int within = i8 & 262143;
    const float* src = (seg == 0) ? WQ : (seg == 1) ? WK : WV;
    const float sc = (seg == 0) ? qscale : 1.0f;
    f32x4 a = *(const f32x4*)(src + within);
    f32x4 b = *(const f32x4*)(src + within + 4);
    bf16x8 v;
    v[0]=(__bf16)(a[0]*sc); v[1]=(__bf16)(a[1]*sc); v[2]=(__bf16)(a[2]*sc); v[3]=(__bf16)(a[3]*sc);
    v[4]=(__bf16)(b[0]*sc); v[5]=(__bf16)(b[1]*sc); v[6]=(__bf16)(b[2]*sc); v[7]=(__bf16)(b[3]*sc);
    *(bf16x8*)(Wb + i8) = v;
}

// ---------------------------------------------------------------------------
// Convert X f32 -> bf16. 16384*512 = 8,388,608 els = 4096 blocks x 256 x 8.
// ---------------------------------------------------------------------------
__global__ void convert_x(const float* __restrict__ X, u16* __restrict__ Xb)
{
    const size_t i8 = ((size_t)blockIdx.x * 256 + threadIdx.x) * 8;
    f32x4 a = *(const f32x4*)(X + i8);
    f32x4 b = *(const f32x4*)(X + i8 + 4);
    bf16x8 v;
    v[0]=(__bf16)a[0]; v[1]=(__bf16)a[1]; v[2]=(__bf16)a[2]; v[3]=(__bf16)a[3];
    v[4]=(__bf16)b[0]; v[5]=(__bf16)b[1]; v[6]=(__bf16)b[2]; v[7]=(__bf16)b[3];
    *(bf16x8*)(Xb + i8) = v;
}

// ---------------------------------------------------------------------------
// GEMM: Q/K [16384][512] bf16; V^T tiled [b][unit16 (256)][d 512][k16] bf16.
// A = Xb bf16, B = Wb bf16, both staged via global_load_lds width-16.
// 128x128 tile, BK=32, 4 waves. grid = (12, 128): x: 0-3 Q, 4-7 K, 8-11 V.
// ---------------------------------------------------------------------------
__global__ __launch_bounds__(256, 2)
void gemm_qkv(const u16* __restrict__ Xb, const u16* __restrict__ Wb,
              u16* __restrict__ Qb, u16* __restrict__ Kb, u16* __restrict__ Vt)
{
    __shared__ u16 As[128*32];
    __shared__ u16 Bs[128*32];
    const int t  = threadIdx.x;
    const int l  = t & 63;
    const int w  = t >> 6;
    const int c  = l & 15;
    const int qd = l >> 4;
    const int m0 = blockIdx.y * 128;
    const int nblk = blockIdx.x;
    const int n0 = nblk * 128;                  // row into Wb[1536]
    const int seg = nblk >> 2;
    const int nw0 = (nblk & 3) * 128;           // feature offset within a W
    const int wm = w >> 1, wn = w & 1;
    const int lr = l >> 2;                      // 0..15 row-within-instr
    const int lc = (l & 3) * 8;                 // 8-el chunk

    f32x4 acc[4][4];
    #pragma unroll
    for (int i = 0; i < 4; i++)
        #pragma unroll
        for (int j = 0; j < 4; j++) acc[i][j] = zero4();

    for (int kk = 0; kk < 512; kk += 32) {
        #pragma unroll
        for (int i = 0; i < 2; ++i) {
            const int r0 = w*32 + i*16;
            load_lds16(&Xb[(size_t)(m0 + r0 + lr)*512 + kk + lc], &As[r0*32]);
            load_lds16(&Wb[(size_t)(n0 + r0 + lr)*512 + kk + lc], &Bs[r0*32]);
        }
        __syncthreads();
        bf16x8 af[4], bfr[4];
        #pragma unroll
        for (int mt = 0; mt < 4; mt++) af[mt]  = *(const bf16x8*)&As[(wm*64 + mt*16 + c)*32 + qd*8];
        #pragma unroll
        for (int nt = 0; nt < 4; nt++) bfr[nt] = *(const bf16x8*)&Bs[(wn*64 + nt*16 + c)*32 + qd*8];
        #pragma unroll
        for (int mt = 0; mt < 4; mt++)
            #pragma unroll
            for (int nt = 0; nt < 4; nt++)
                acc[mt][nt] = __builtin_amdgcn_mfma_f32_16x16x32_bf16(af[mt], bfr[nt], acc[mt][nt], 0, 0, 0);
        __syncthreads();
    }

    #pragma unroll
    for (int mt = 0; mt < 4; mt++) {
        #pragma unroll
        for (int nt = 0; nt < 4; nt++) {
            const int gm0 = m0 + wm*64 + mt*16 + qd*4;       // token row of reg 0
            const int gn  = nw0 + wn*64 + nt*16 + c;         // feature 0..511
            if (seg == 0) {
                #pragma unroll
                for (int r = 0; r < 4; r++)
                    Qb[(size_t)(gm0 + r)*512 + gn] = bf16bits(acc[mt][nt][r]);
            } else if (seg == 1) {
                #pragma unroll
                for (int r = 0; r < 4; r++)
                    Kb[(size_t)(gm0 + r)*512 + gn] = bf16bits(acc[mt][nt][r]);
            } else {
                const int bb   = gm0 >> 12;
                const int ss   = gm0 & 4095;
                const int unit = ss >> 4;                    // 16-key unit
                const int k16  = ss & 15;                    // 4-aligned
                u16x4 pk;
                pk[0] = bf16bits(acc[mt][nt][0]);
                pk[1] = bf16bits(acc[mt][nt][1]);
                pk[2] = bf16bits(acc[mt][nt][2]);
                pk[3] = bf16bits(acc[mt][nt][3]);
                *(u16x4*)&Vt[((size_t)(bb*256 + unit)*512 + gn)*16 + k16] = pk;
            }
        }
    }
}

// ---------------------------------------------------------------------------
// Flash attention chunk, transposed-MFMA design, causal.
// Block = 4 waves x 16-row strips (M=64 rows, q-tile qt). KV-16 units,
// K+V double-buffered in LDS (global_load_lds), ONE barrier per unit.
// S^T = K Q^T (A=K,B=Q): softmax = VALU reg-reduce + 2 shfls; alpha per-lane;
// P feeds PV directly from registers (B-operand of 16x16x16, A=V^T) -> o^T.
// Chunking: 4 chunks per (b,qt), each EXACTLY qt+1 units. grid 1024:
// qt = 63-(x>>4) heavy-first, j=(x>>2)&3, b = x&3 (XCD-pinned batch).
// Writes unnormalized partial O (bf16) + m, l per row.
// ---------------------------------------------------------------------------
__global__ __launch_bounds__(256, 2)
void attn_chunk(const u16* __restrict__ Qb, const u16* __restrict__ Kb,
                const u16* __restrict__ Vt, u16* __restrict__ Op,
                float* __restrict__ Mp, float* __restrict__ Lp)
{
    __shared__ u16 Ks[2][16*520];   // 33,280 B (rows padded 520; 1KB contiguous)
    __shared__ u16 Vs[2][512*16];   // 32,768 B  V^T [d][k16]

    const int t  = threadIdx.x;
    const int l  = t & 63;
    const int w  = t >> 6;          // strip: rows [16w,16w+16) of q-tile
    const int c  = l & 15;
    const int qd = l >> 4;
    const int x  = blockIdx.x;
    const int qt = 63 - (x >> 4);   // heavy-first
    const int j  = (x >> 2) & 3;
    const int b  = x & 3;
    const int u   = qt + 1;         // units per chunk (exact)
    const int it0 = j * u;
    const int it1 = it0 + u - 1;
    const int q0  = qt * 64;
    const int kmax = 4*qt + w;      // last unit with any unmasked key for strip

    // Q fragments (B-operand: n=row=c, k=qd*8+jj), register-resident
    bf16x8 qf[16];
    {
        const size_t qrow = (size_t)(b*4096 + q0 + w*16 + c);
        #pragma unroll
        for (int ks = 0; ks < 16; ++ks)
            qf[ks] = *(const bf16x8*)&Qb[qrow*512 + ks*32 + qd*8];
    }

    f32x4 o[32];                    // o^T: lane c = row; reg (nt,r): d = nt*16+qd*4+r
    #pragma unroll
    for (int nt = 0; nt < 32; nt++) o[nt] = zero4();
    float m_c = NEGINF, l_c = 0.f;

    const u16* Kg = &Kb[(size_t)(b*4096)*512];
    const u16* Vg = &Vt[(size_t)(b*256)*8192];

    // stage unit it0 -> buf 0 (wave w: 4 K-rows + 4 V-chunks of 32 d-rows)
    #pragma unroll
    for (int i = 0; i < 4; i++) {
        const int ch = w*4 + i;
        load_lds16(Kg + ((size_t)(it0*16 + ch))*512 + l*8, &Ks[0][ch*520]);
        load_lds16(Vg + (size_t)it0*8192 + ch*512 + l*8, &Vs[0][ch*512]);
    }
    __syncthreads();

    for (int it = it0; it <= it1; ++it) {
        const int buf = (it - it0) & 1;
        // issue next unit's staging into other buffer (drains at end barrier)
        if (it < it1) {
            #pragma unroll
            for (int i = 0; i < 4; i++) {
                const int ch = w*4 + i;
                load_lds16(Kg + ((size_t)((it+1)*16 + ch))*512 + l*8, &Ks[buf^1][ch*520]);
                load_lds16(Vg + (size_t)(it+1)*8192 + ch*512 + l*8, &Vs[buf^1][ch*512]);
            }
        }

        if (it <= kmax) {           // skip fully-masked units (wave-uniform)
            // ---- S^T = K Q^T : regs = keys qd*4+r, lane c = row
            f32x4 sa = zero4(), sb = zero4();
            #pragma unroll
            for (int ks = 0; ks < 16; ks += 2) {
                bf16x8 kfa = *(const bf16x8*)&Ks[buf][c*520 + ks*32 + qd*8];
                sa = __builtin_amdgcn_mfma_f32_16x16x32_bf16(kfa, qf[ks], sa, 0, 0, 0);
                bf16x8 kfb = *(const bf16x8*)&Ks[buf][c*520 + (ks+1)*32 + qd*8];
                sb = __builtin_amdgcn_mfma_f32_16x16x32_bf16(kfb, qf[ks+1], sb, 0, 0, 0);
            }
            f32x4 s;
            s[0]=sa[0]+sb[0]; s[1]=sa[1]+sb[1]; s[2]=sa[2]+sb[2]; s[3]=sa[3]+sb[3];
            if (it == kmax) {       // diagonal: mask key(qd*4+r) > row(c)
                #pragma unroll
                for (int r = 0; r < 4; r++)
                    if (qd*4 + r > c) s[r] = NEGINF;
            }

            // ---- online softmax: reduce over regs + 2 shfls (keys on qd axis)
            float mx = fmaxf(fmaxf(s[0], s[1]), fmaxf(s[2], s[3]));
            mx = fmaxf(mx, __shfl_xor(mx, 16));
            mx = fmaxf(mx, __shfl_xor(mx, 32));
            const float mnew = fmaxf(m_c, mx);
            const float al = exp2f((m_c - mnew) * LOG2E);
            const float p0 = exp2f((s[0] - mnew) * LOG2E);
            const float p1 = exp2f((s[1] - mnew) * LOG2E);
            const float p2 = exp2f((s[2] - mnew) * LOG2E);
            const float p3 = exp2f((s[3] - mnew) * LOG2E);
            float ps = (p0 + p1) + (p2 + p3);
            ps += __shfl_xor(ps, 16);
            ps += __shfl_xor(ps, 32);
            l_c = l_c * al + ps;
            m_c = mnew;
            bf16x4 pf;
            pf[0]=(__bf16)p0; pf[1]=(__bf16)p1; pf[2]=(__bf16)p2; pf[3]=(__bf16)p3;

            // ---- rescale + PV: o^T[d][row] += V^T-frag x P-frag (K=16)
            #pragma unroll
            for (int nt = 0; nt < 32; nt++) {
                bf16x4 vf = *(const bf16x4*)&Vs[buf][(nt*16 + c)*16 + qd*4];
                o[nt][0] *= al; o[nt][1] *= al; o[nt][2] *= al; o[nt][3] *= al;
                o[nt] = mfma16(vf, pf, o[nt]);
            }
        }
        __syncthreads();            // staging of it+1 done; buf free for it+2
    }

    // ---- write unnormalized partials + m, l
    const size_t ob = ((size_t)((b*64 + qt)*4 + j))*64;
    if (qd == 0) {
        Mp[ob + w*16 + c] = m_c;
        Lp[ob + w*16 + c] = l_c;
    }
    #pragma unroll
    for (int nt = 0; nt < 32; nt++) {
        u16x4 pk;
        pk[0] = bf16bits(o[nt][0]); pk[1] = bf16bits(o[nt][1]);
        pk[2] = bf16bits(o[nt][2]); pk[3] = bf16bits(o[nt][3]);
        *(u16x4*)&Op[(ob + w*16 + c)*512 + nt*16 + qd*4] = pk;
    }
}

// ---------------------------------------------------------------------------
// Combine partial chunks: out = sum_j e^{m_j-M} O_j / sum_j e^{m_j-M} l_j.
// grid (64, 4) = (qt, b), 256 threads. All 4 chunks always present.
// ---------------------------------------------------------------------------
__global__ __launch_bounds__(256)
void combine(const u16* __restrict__ Op, const float* __restrict__ Mp,
             const float* __restrict__ Lp, float* __restrict__ out)
{
    __shared__ float sc[4][64];
    const int t  = threadIdx.x;
    const int qt = blockIdx.x;
    const int b  = blockIdx.y;
    const int base = (b*64 + qt)*4;

    if (t < 64) {
        float mj[4], lj[4];
        float M = NEGINF;
        for (int j = 0; j < 4; j++) {
            mj[j] = Mp[(size_t)(base + j)*64 + t];
            lj[j] = Lp[(size_t)(base + j)*64 + t];
            M = fmaxf(M, mj[j]);
        }
        float denom = 0.f;
        float wj[4];
        for (int j = 0; j < 4; j++) {
            wj[j] = exp2f((mj[j] - M) * LOG2E);
            denom += wj[j] * lj[j];
        }
        const float inv = 1.0f / denom;
        for (int j = 0; j < 4; j++) sc[j][t] = wj[j] * inv;
    }
    __syncthreads();

    const int c4 = (t & 127) * 4;
    const int r0 = (t >> 7) * 32;
    for (int r = r0; r < r0 + 32; ++r) {
        float a0 = 0.f, a1 = 0.f, a2 = 0.f, a3 = 0.f;
        for (int j = 0; j < 4; j++) {
            const float s = sc[j][r];
            u16x4 v = *(const u16x4*)&Op[((size_t)(base + j)*64 + r)*512 + c4];
            a0 += s * bits2f(v[0]); a1 += s * bits2f(v[1]);
            a2 += s * bits2f(v[2]); a3 += s * bits2f(v[3]);
        }
        f32x4 res; res[0]=a0; res[1]=a1; res[2]=a2; res[3]=a3;
        *(f32x4*)&out[((size_t)(b*4096 + qt*64 + r))*512 + c4] = res;
    }
}

extern "C" void kernel_launch(void* const* d_in, const int* in_sizes, int n_in,
                              void* d_out, int out_size, void* d_ws, size_t ws_size,
                              hipStream_t stream)
{
    (void)in_sizes; (void)n_in; (void)out_size; (void)ws_size;
    const float* X  = (const float*)d_in[0];
    const float* WQ = (const float*)d_in[1];
    const float* WK = (const float*)d_in[2];
    const float* WV = (const float*)d_in[3];
    float* out = (float*)d_out;
    char* ws = (char*)d_ws;
    const size_t MB = 1024*1024;
    u16*   Qb = (u16*)(ws);                    // [0,16) MB  bf16 [16384][512], Q pre-scaled
    u16*   Kb = (u16*)(ws + 16*MB);            // [16,32) MB bf16 [16384][512]
    u16*   Vt = (u16*)(ws + 32*MB);            // [32,48) MB bf16 V^T [4][256][512][16]
    u16*   Wb = (u16*)(ws + 48*MB);            // 1.5 MB bf16 [1536][512]
    float* Mp = (float*)(ws + 50*MB);          // 256 KB [4][64][4][64]
    float* Lp = (float*)(ws + 51*MB);          // 256 KB
    u16*   Op = (u16*)(ws + 52*MB);            // 64 MB bf16 [4][64][4][64][512] -> ws 116 MB
    u16*   Xb = (u16*)(ws + 52*MB);            // 16 MB, ALIASES Op (gemm phase only)

    convert_w<<<dim3(384), 256, 0, stream>>>(WQ, WK, WV, Wb);
    convert_x<<<dim3(4096), 256, 0, stream>>>(X, Xb);
    gemm_qkv<<<dim3(12, 128), 256, 0, stream>>>(Xb, Wb, Qb, Kb, Vt);
    attn_chunk<<<dim3(1024), 256, 0, stream>>>(Qb, Kb, Vt, Op, Mp, Lp);
    combine<<<dim3(64, 4), 256, 0, stream>>>(Op, Mp, Lp, out);
}

// Round 7
// 308.709 us; speedup vs baseline: 3.8652x; 1.1186x over previous
//
#include <hip/hip_runtime.h>

typedef __attribute__((ext_vector_type(8))) __bf16 bf16x8;
typedef __attribute__((ext_vector_type(4))) float f32x4;
typedef unsigned short u16;
typedef __attribute__((ext_vector_type(4))) u16 u16x4;

#define MASKVAL -3.0e38f
#define MINIT   -1.0e38f
#define LOG2E 1.4426950408889634f

__device__ inline f32x4 zero4() { f32x4 v; v[0]=0.f; v[1]=0.f; v[2]=0.f; v[3]=0.f; return v; }

__device__ inline u16 bf16bits(float x) {
    union { __bf16 h; u16 u; } cv; cv.h = (__bf16)x; return cv.u;
}
__device__ inline float bits2f(u16 b) {
    union { unsigned u; float f; } cv; cv.u = ((unsigned)b) << 16; return cv.f;
}

// async 16B/lane global -> LDS (lds dest = wave-uniform base + lane*16)
__device__ inline void load_lds16(const u16* g, u16* l) {
    __builtin_amdgcn_global_load_lds((const __attribute__((address_space(1))) void*)g,
                                     (__attribute__((address_space(3))) void*)l, 16, 0, 0);
}

// ---------------------------------------------------------------------------
// Convert W_Q (pre-scaled by 1/sqrt(512)), W_K, W_V to bf16 concat [1536][512].
// ---------------------------------------------------------------------------
__global__ void convert_w(const float* __restrict__ WQ, const float* __restrict__ WK,
                          const float* __restrict__ WV, u16* __restrict__ Wb)
{
    const float qscale = 0.044194173824159216f;  // 1/sqrt(512)
    const int i8 = (blockIdx.x * 256 + threadIdx.x) * 8;
    const int seg = i8 >> 18;                    // 262144 els per W
    const int within = i8 & 262143;
    const float* src = (seg == 0) ? WQ : (seg == 1) ? WK : WV;
    const float sc = (seg == 0) ? qscale : 1.0f;
    f32x4 a = *(const f32x4*)(src + within);
    f32x4 b = *(const f32x4*)(src + within + 4);
    bf16x8 v;
    v[0]=(__bf16)(a[0]*sc); v[1]=(__bf16)(a[1]*sc); v[2]=(__bf16)(a[2]*sc); v[3]=(__bf16)(a[3]*sc);
    v[4]=(__bf16)(b[0]*sc); v[5]=(__bf16)(b[1]*sc); v[6]=(__bf16)(b[2]*sc); v[7]=(__bf16)(b[3]*sc);
    *(bf16x8*)(Wb + i8) = v;
}

// ---------------------------------------------------------------------------
// Convert X f32 -> bf16. 16384*512 = 8,388,608 els = 4096 blocks x 256 x 8.
// ---------------------------------------------------------------------------
__global__ void convert_x(const float* __restrict__ X, u16* __restrict__ Xb)
{
    const size_t i8 = ((size_t)blockIdx.x * 256 + threadIdx.x) * 8;
    f32x4 a = *(const f32x4*)(X + i8);
    f32x4 b = *(const f32x4*)(X + i8 + 4);
    bf16x8 v;
    v[0]=(__bf16)a[0]; v[1]=(__bf16)a[1]; v[2]=(__bf16)a[2]; v[3]=(__bf16)a[3];
    v[4]=(__bf16)b[0]; v[5]=(__bf16)b[1]; v[6]=(__bf16)b[2]; v[7]=(__bf16)b[3];
    *(bf16x8*)(Xb + i8) = v;
}

// ---------------------------------------------------------------------------
// GEMM: Q/K [16384][512] bf16; V^T tiled [b][u32 (128)][512 d][32 k] bf16.
// A = Xb bf16, B = Wb bf16, both staged via global_load_lds width-16.
// 128x128 tile, BK=32, 4 waves. grid = (12, 128): x: 0-3 Q, 4-7 K, 8-11 V.
// ---------------------------------------------------------------------------
__global__ __launch_bounds__(256, 2)
void gemm_qkv(const u16* __restrict__ Xb, const u16* __restrict__ Wb,
              u16* __restrict__ Qb, u16* __restrict__ Kb, u16* __restrict__ Vt)
{
    __shared__ u16 As[128*32];
    __shared__ u16 Bs[128*32];
    const int t  = threadIdx.x;
    const int l  = t & 63;
    const int w  = t >> 6;
    const int c  = l & 15;
    const int qd = l >> 4;
    const int m0 = blockIdx.y * 128;
    const int nblk = blockIdx.x;
    const int n0 = nblk * 128;                  // row into Wb[1536]
    const int seg = nblk >> 2;
    const int nw0 = (nblk & 3) * 128;           // feature offset within a W
    const int wm = w >> 1, wn = w & 1;
    const int lr = l >> 2;                      // 0..15 row-within-instr
    const int lc = (l & 3) * 8;                 // 8-el chunk

    f32x4 acc[4][4];
    #pragma unroll
    for (int i = 0; i < 4; i++)
        #pragma unroll
        for (int j = 0; j < 4; j++) acc[i][j] = zero4();

    for (int kk = 0; kk < 512; kk += 32) {
        #pragma unroll
        for (int i = 0; i < 2; ++i) {
            const int r0 = w*32 + i*16;
            load_lds16(&Xb[(size_t)(m0 + r0 + lr)*512 + kk + lc], &As[r0*32]);
            load_lds16(&Wb[(size_t)(n0 + r0 + lr)*512 + kk + lc], &Bs[r0*32]);
        }
        __syncthreads();
        bf16x8 af[4], bfr[4];
        #pragma unroll
        for (int mt = 0; mt < 4; mt++) af[mt]  = *(const bf16x8*)&As[(wm*64 + mt*16 + c)*32 + qd*8];
        #pragma unroll
        for (int nt = 0; nt < 4; nt++) bfr[nt] = *(const bf16x8*)&Bs[(wn*64 + nt*16 + c)*32 + qd*8];
        #pragma unroll
        for (int mt = 0; mt < 4; mt++)
            #pragma unroll
            for (int nt = 0; nt < 4; nt++)
                acc[mt][nt] = __builtin_amdgcn_mfma_f32_16x16x32_bf16(af[mt], bfr[nt], acc[mt][nt], 0, 0, 0);
        __syncthreads();
    }

    #pragma unroll
    for (int mt = 0; mt < 4; mt++) {
        #pragma unroll
        for (int nt = 0; nt < 4; nt++) {
            const int gm0 = m0 + wm*64 + mt*16 + qd*4;       // token row of reg 0
            const int gn  = nw0 + wn*64 + nt*16 + c;         // feature 0..511
            if (seg == 0) {
                #pragma unroll
                for (int r = 0; r < 4; r++)
                    Qb[(size_t)(gm0 + r)*512 + gn] = bf16bits(acc[mt][nt][r]);
            } else if (seg == 1) {
                #pragma unroll
                for (int r = 0; r < 4; r++)
                    Kb[(size_t)(gm0 + r)*512 + gn] = bf16bits(acc[mt][nt][r]);
            } else {
                const int bb   = gm0 >> 12;
                const int ss   = gm0 & 4095;
                const int unit = ss >> 5;                    // 32-key unit
                const int kl   = ss & 31;                    // 4-aligned
                u16x4 pk;
                pk[0] = bf16bits(acc[mt][nt][0]);
                pk[1] = bf16bits(acc[mt][nt][1]);
                pk[2] = bf16bits(acc[mt][nt][2]);
                pk[3] = bf16bits(acc[mt][nt][3]);
                *(u16x4*)&Vt[((size_t)(bb*128 + unit)*512 + gn)*32 + kl] = pk;
            }
        }
    }
}

// ---------------------------------------------------------------------------
// Flash attention chunk v7, causal. M=64 rows, 4 waves.
// Unit = 32 keys. S^T = K Q^T per 16-row strip (wave w owns rows [16w,16w+16)
// of the softmax); PV is d-split: wave w computes o for d in [128w,128w+128)
// over ALL 64 rows, P broadcast via LDS (dbuf), V read per-wave from global
// (coalesced b128, L2-hot). K dbuf in LDS via global_load_lds. One barrier
// per unit. Frozen-m softmax: no per-unit rescale/max-reduce; ballot-guarded
// slow path publishes per-strip alpha+flag.
// grid 1024: qt = 63-(x>>4) heavy-first, j=(x>>2)&3, b=x&3.
// ---------------------------------------------------------------------------
__global__ __launch_bounds__(256, 2)
void attn_chunk(const u16* __restrict__ Qb, const u16* __restrict__ Kb,
                const u16* __restrict__ Vt, u16* __restrict__ Op,
                float* __restrict__ Mp, float* __restrict__ Lp)
{
    __shared__ u16 Ks[2][32*520];   // 66,560 B  K rows padded 520 (1KB contiguous)
    __shared__ u16 Ps[2][64*40];    // 10,240 B  P[row][32 keys + pad 8]
    __shared__ float Al[2][64];     //  512 B    per-row alpha (slow path)
    __shared__ unsigned Fl[2][4];   //   32 B    per-strip rescale flag

    const int t  = threadIdx.x;
    const int l  = t & 63;
    const int w  = t >> 6;
    const int c  = l & 15;
    const int qd = l >> 4;
    const int x  = blockIdx.x;
    const int qt = 63 - (x >> 4);
    const int j  = (x >> 2) & 3;
    const int b  = x & 3;
    const int U  = 2*qt + 2;                 // 32-key units total
    const int uc = (U + 3) >> 2;
    const int it0 = j * uc;
    if (it0 >= U) return;
    const int it1 = min(U, it0 + uc) - 1;
    const int q0 = qt * 64;
    const int itSkip = 2*qt + (w >> 1);      // last unit with any valid key for strip w

    // Q fragments (B-operand: n=row=c, k=qd*8+jj), register-resident
    bf16x8 qf[16];
    {
        const size_t qrow = (size_t)(b*4096 + q0 + w*16 + c);
        #pragma unroll
        for (int ks = 0; ks < 16; ++ks)
            qf[ks] = *(const bf16x8*)&Qb[qrow*512 + ks*32 + qd*8];
    }

    f32x4 o[8][4];                  // [dt][rt]: d = w*128+dt*16+qd*4+r, row = rt*16+c
    #pragma unroll
    for (int dt = 0; dt < 8; dt++)
        #pragma unroll
        for (int rt = 0; rt < 4; rt++) o[dt][rt] = zero4();
    float m_c = MINIT, l_c = 0.f;

    const u16* Kg = Kb + (size_t)(b*4096)*512;
    const u16* Vg = Vt + (size_t)(b*128)*16384;

    // prologue: stage K(it0); wave w stages key-rows [8w, 8w+8)
    #pragma unroll
    for (int i = 0; i < 8; i++) {
        const int row = w*8 + i;
        load_lds16(Kg + ((size_t)(it0*32 + row))*512 + l*8, &Ks[0][row*520]);
    }

    for (int it = it0; it <= it1 + 1; ++it) {
        const int pb = (it - it0) & 1;
        __syncthreads();            // K(it) staged; P(it-1)/Al/Fl published

        // ---- V loads for PV(it-1): 8 coalesced b128, own d-quarter
        bf16x8 vf[8];
        if (it > it0) {
            const u16* vu = Vg + (size_t)(it-1)*16384 + qd*8;
            #pragma unroll
            for (int dt = 0; dt < 8; dt++)
                vf[dt] = *(const bf16x8*)(vu + (w*128 + dt*16 + c)*32);
        }
        // ---- issue K staging (it+1)
        if (it < it1) {
            #pragma unroll
            for (int i = 0; i < 8; i++) {
                const int row = w*8 + i;
                load_lds16(Kg + ((size_t)((it+1)*32 + row))*512 + l*8, &Ks[pb^1][row*520]);
            }
        }

        // ---- S^T + softmax for unit it
        if (it <= it1) {
            if (it <= itSkip) {
                f32x4 s0 = zero4(), s1 = zero4();
                #pragma unroll
                for (int ks = 0; ks < 16; ++ks) {
                    bf16x8 k0 = *(const bf16x8*)&Ks[pb][c*520 + ks*32 + qd*8];
                    s0 = __builtin_amdgcn_mfma_f32_16x16x32_bf16(k0, qf[ks], s0, 0, 0, 0);
                    bf16x8 k1 = *(const bf16x8*)&Ks[pb][(16 + c)*520 + ks*32 + qd*8];
                    s1 = __builtin_amdgcn_mfma_f32_16x16x32_bf16(k1, qf[ks], s1, 0, 0, 0);
                }
                const int rowg = q0 + w*16 + c;
                if (32*it + 31 > rowg) {       // causal mask (partial unit)
                    const int k0g = 32*it + qd*4;
                    #pragma unroll
                    for (int r = 0; r < 4; r++) {
                        if (k0g + r      > rowg) s0[r] = MASKVAL;
                        if (k0g + 16 + r > rowg) s1[r] = MASKVAL;
                    }
                }
                float mloc = fmaxf(fmaxf(fmaxf(s0[0], s0[1]), fmaxf(s0[2], s0[3])),
                                   fmaxf(fmaxf(s1[0], s1[1]), fmaxf(s1[2], s1[3])));
                if (__ballot(mloc > m_c + 20.f)) {   // slow path (first unit + rare drift)
                    float rm = mloc;
                    rm = fmaxf(rm, __shfl_xor(rm, 16));
                    rm = fmaxf(rm, __shfl_xor(rm, 32));
                    const float mnew = fmaxf(m_c, rm);
                    const float al = exp2f((m_c - mnew) * LOG2E);
                    l_c *= al;
                    m_c = mnew;
                    if (qd == 0) Al[pb][w*16 + c] = al;
                    if (l == 0) Fl[pb][w] = 1u;
                } else {
                    if (l == 0) Fl[pb][w] = 0u;
                }
                const float p0 = exp2f((s0[0] - m_c) * LOG2E);
                const float p1 = exp2f((s0[1] - m_c) * LOG2E);
                const float p2 = exp2f((s0[2] - m_c) * LOG2E);
                const float p3 = exp2f((s0[3] - m_c) * LOG2E);
                const float p4 = exp2f((s1[0] - m_c) * LOG2E);
                const float p5 = exp2f((s1[1] - m_c) * LOG2E);
                const float p6 = exp2f((s1[2] - m_c) * LOG2E);
                const float p7 = exp2f((s1[3] - m_c) * LOG2E);
                l_c += ((p0 + p1) + (p2 + p3)) + ((p4 + p5) + (p6 + p7));
                u16x4 pka, pkb;
                pka[0]=bf16bits(p0); pka[1]=bf16bits(p1); pka[2]=bf16bits(p2); pka[3]=bf16bits(p3);
                pkb[0]=bf16bits(p4); pkb[1]=bf16bits(p5); pkb[2]=bf16bits(p6); pkb[3]=bf16bits(p7);
                *(u16x4*)&Ps[pb][(w*16 + c)*40 + qd*4]      = pka;
                *(u16x4*)&Ps[pb][(w*16 + c)*40 + 16 + qd*4] = pkb;
            } else {
                // fully-masked unit for this strip: publish zero P, no rescale
                u16x4 z; z[0]=0; z[1]=0; z[2]=0; z[3]=0;
                *(u16x4*)&Ps[pb][(w*16 + c)*40 + qd*4]      = z;
                *(u16x4*)&Ps[pb][(w*16 + c)*40 + 16 + qd*4] = z;
                if (l == 0) Fl[pb][w] = 0u;
            }
        }

        // ---- PV(it-1): o[dt][rt] += V^T-frag x P-frag (K=32)
        if (it > it0) {
            const int ppb = pb ^ 1;
            bf16x8 pfr[4];
            #pragma unroll
            for (int rt = 0; rt < 4; rt++)
                pfr[rt] = *(const bf16x8*)&Ps[ppb][(rt*16 + c)*40 + qd*8];
            #pragma unroll
            for (int rt = 0; rt < 4; rt++) {
                if (Fl[ppb][rt]) {
                    const float al = Al[ppb][rt*16 + c];
                    #pragma unroll
                    for (int dt = 0; dt < 8; dt++) {
                        o[dt][rt][0] *= al; o[dt][rt][1] *= al;
                        o[dt][rt][2] *= al; o[dt][rt][3] *= al;
                    }
                }
            }
            #pragma unroll
            for (int dt = 0; dt < 8; dt++)
                #pragma unroll
                for (int rt = 0; rt < 4; rt++)
                    o[dt][rt] = __builtin_amdgcn_mfma_f32_16x16x32_bf16(vf[dt], pfr[rt], o[dt][rt], 0, 0, 0);
        }
    }

    // ---- epilogue: reduce l over qd, write m/l + unnormalized partials
    l_c += __shfl_xor(l_c, 16);
    l_c += __shfl_xor(l_c, 32);
    const size_t ob = ((size_t)((b*64 + qt)*4 + j))*64;
    if (qd == 0) {
        Mp[ob + w*16 + c] = m_c;
        Lp[ob + w*16 + c] = l_c;
    }
    #pragma unroll
    for (int dt = 0; dt < 8; dt++) {
        #pragma unroll
        for (int rt = 0; rt < 4; rt++) {
            u16x4 pk;
            pk[0] = bf16bits(o[dt][rt][0]); pk[1] = bf16bits(o[dt][rt][1]);
            pk[2] = bf16bits(o[dt][rt][2]); pk[3] = bf16bits(o[dt][rt][3]);
            *(u16x4*)&Op[(ob + rt*16 + c)*512 + w*128 + dt*16 + qd*4] = pk;
        }
    }
}

// ---------------------------------------------------------------------------
// Combine partial chunks: out = sum_j e^{m_j-M} O_j / sum_j e^{m_j-M} l_j.
// grid (64, 4) = (qt, b), 256 threads.
// ---------------------------------------------------------------------------
__global__ __launch_bounds__(256)
void combine(const u16* __restrict__ Op, const float* __restrict__ Mp,
             const float* __restrict__ Lp, float* __restrict__ out)
{
    __shared__ float sc[4][64];
    const int t  = threadIdx.x;
    const int qt = blockIdx.x;
    const int b  = blockIdx.y;
    const int U  = 2*qt + 2;
    const int uc = (U + 3) >> 2;
    const int nc = (U + uc - 1) / uc;          // non-empty chunks, <= 4
    const int base = (b*64 + qt)*4;

    if (t < 64) {
        float mj[4], lj[4];
        float M = MINIT;
        for (int j = 0; j < nc; j++) {
            mj[j] = Mp[(size_t)(base + j)*64 + t];
            lj[j] = Lp[(size_t)(base + j)*64 + t];
            M = fmaxf(M, mj[j]);
        }
        float denom = 0.f;
        float wj[4];
        for (int j = 0; j < nc; j++) {
            wj[j] = exp2f((mj[j] - M) * LOG2E);
            denom += wj[j] * lj[j];
        }
        const float inv = 1.0f / denom;
        for (int j = 0; j < nc; j++) sc[j][t] = wj[j] * inv;
    }
    __syncthreads();

    const int c4 = (t & 127) * 4;
    const int r0 = (t >> 7) * 32;
    for (int r = r0; r < r0 + 32; ++r) {
        float a0 = 0.f, a1 = 0.f, a2 = 0.f, a3 = 0.f;
        for (int j = 0; j < nc; j++) {
            const float s = sc[j][r];
            u16x4 v = *(const u16x4*)&Op[((size_t)(base + j)*64 + r)*512 + c4];
            a0 += s * bits2f(v[0]); a1 += s * bits2f(v[1]);
            a2 += s * bits2f(v[2]); a3 += s * bits2f(v[3]);
        }
        f32x4 res; res[0]=a0; res[1]=a1; res[2]=a2; res[3]=a3;
        *(f32x4*)&out[((size_t)(b*4096 + qt*64 + r))*512 + c4] = res;
    }
}

extern "C" void kernel_launch(void* const* d_in, const int* in_sizes, int n_in,
                              void* d_out, int out_size, void* d_ws, size_t ws_size,
                              hipStream_t stream)
{
    (void)in_sizes; (void)n_in; (void)out_size; (void)ws_size;
    const float* X  = (const float*)d_in[0];
    const float* WQ = (const float*)d_in[1];
    const float* WK = (const float*)d_in[2];
    const float* WV = (const float*)d_in[3];
    float* out = (float*)d_out;
    char* ws = (char*)d_ws;
    const size_t MB = 1024*1024;
    u16*   Qb = (u16*)(ws);                    // [0,16) MB  bf16 [16384][512], Q pre-scaled
    u16*   Kb = (u16*)(ws + 16*MB);            // [16,32) MB bf16 [16384][512]
    u16*   Vt = (u16*)(ws + 32*MB);            // [32,48) MB bf16 V^T [4][128][512][32]
    u16*   Wb = (u16*)(ws + 48*MB);            // 1.5 MB bf16 [1536][512]
    float* Mp = (float*)(ws + 50*MB);          // 256 KB [4][64][4][64]
    float* Lp = (float*)(ws + 51*MB);          // 256 KB
    u16*   Op = (u16*)(ws + 52*MB);            // 64 MB bf16 [4][64][4][64][512] -> ws 116 MB
    u16*   Xb = (u16*)(ws + 52*MB);            // 16 MB, ALIASES Op (gemm phase only)

    convert_w<<<dim3(384), 256, 0, stream>>>(WQ, WK, WV, Wb);
    convert_x<<<dim3(4096), 256, 0, stream>>>(X, Xb);
    gemm_qkv<<<dim3(12, 128), 256, 0, stream>>>(Xb, Wb, Qb, Kb, Vt);
    attn_chunk<<<dim3(1024), 256, 0, stream>>>(Qb, Kb, Vt, Op, Mp, Lp);
    combine<<<dim3(64, 4), 256, 0, stream>>>(Op, Mp, Lp, out);
}